// Round 12
// baseline (392.608 us; speedup 1.0000x reference)
//
#include <hip/hip_runtime.h>
#include <hip/hip_bf16.h>

#define OUT_F 64
#define IN_F 64
#define M_PTS 20
#define BATCH 1024
#define NEPB (IN_F * M_PTS)        // 1280 coefficient entries per o
#define REP 32                     // DIAGNOSTIC amplification of phase 2

#if __has_builtin(__builtin_amdgcn_exp2f)
#define EXP2(x) __builtin_amdgcn_exp2f(x)
#else
#define EXP2(x) exp2f(x)
#endif
#define LOG2E 1.4426950408889634f

static __device__ __forceinline__ unsigned f2bf(float f) {
    union { float f; unsigned u; } v; v.f = f;
    unsigned r = v.u + 0x7fffu + ((v.u >> 16) & 1u);   // rne
    return r >> 16;
}
static __device__ __forceinline__ float bflo(unsigned p) {
    union { unsigned u; float f; } v; v.u = p << 16; return v.f;
}
static __device__ __forceinline__ float bfhi(unsigned p) {
    union { unsigned u; float f; } v; v.u = p & 0xffff0000u; return v.f;
}

// Hot-loop recurrence (validated r5-r10, absmax 3.1e-2 vs 8.5e-2 threshold).
#define BODY(P)                                                              \
    {                                                                        \
        float xb0 = xg[((2 * (P)) << 6) + lane];                             \
        float xb1 = xg[((2 * (P) + 1) << 6) + lane];                         \
        float dx0 = fmaf(s, xb0, -sz0);                                      \
        float dx1 = fmaf(s, xb1, -sz0);                                      \
        float t0  = EXP2(-(dx0 * dx0));                                      \
        float t1  = EXP2(-(dx1 * dx1));                                      \
        float w0  = EXP2(fminf(fmaf(cu1, dx0, cu0), 60.0f));                 \
        float w1  = EXP2(fminf(fmaf(cu1, dx1, cu0), 60.0f));                 \
        float em0 = 0.0f, em1 = 0.0f, ev0 = 0.0f, ev1 = 0.0f;                \
        _Pragma("unroll")                                                    \
        for (int m = 0; m < M_PTS; ++m) {                                    \
            unsigned c = cp[m];                                              \
            float qmc = bflo(c);                                             \
            float B   = bfhi(c);                                             \
            em0 = fmaf(qmc, t0, em0);                                        \
            em1 = fmaf(qmc, t1, em1);                                        \
            ev0 = fmaf(B, t0 * t0, ev0);                                     \
            ev1 = fmaf(B, t1 * t1, ev1);                                     \
            if (m < M_PTS - 1) { t0 *= w0; t1 *= w1; w0 *= v; w1 *= v; }     \
        }                                                                    \
        qa[2 * (P)]     = em0;                                               \
        qa[2 * (P) + 1] = em1;                                               \
        qa[8 + 2 * (P)] = fmaxf(ev0, 0.0f);                                  \
        qa[9 + 2 * (P)] = fmaxf(ev1, 0.0f);                                  \
    }

// DIAGNOSTIC build of the r10 fused kernel: phase 2 repeated REP times with
// asm-laundered inputs (defeats LICM); stores are idempotent (same values
// each rep) so output stays correct. Purpose: (a) t_hot from the dur slope,
// (b) push the kernel past the 39us fill kernels into rocprof top-5.
__global__ __launch_bounds__(512, 8) void gpkan_fused_diag(
    const float* __restrict__ x, const float* __restrict__ z,
    const float* __restrict__ q_mu, const float* __restrict__ q_log_var,
    const float* __restrict__ log_scale, const float* __restrict__ log_variance,
    float* __restrict__ out)
{
    __shared__ unsigned c_lds[NEPB];       // [m][i] = m*64 + i
    __shared__ float4   aux_lds[IN_F];

    const int blk = blockIdx.x;
    const int o   = blk >> 4;
    const int bc  = blk & 15;
    const int tid = threadIdx.x;

    // ---- phase 1: coefficients (runs once; NOT amplified) ----
    const int base = o * NEPB;
    #pragma unroll
    for (int kk = 0; kk < 3; ++kk) {
        int idx = tid + (kk << 9);
        if (idx < NEPB) {
            int i = idx / M_PTS;
            int m = idx - i * M_PTS;
            int e = (o << 6) + i;

            float ell  = fmaxf(EXP2(log_scale[e] * LOG2E), 0.1f);
            float l2   = ell * ell;
            float sig2 = fmaxf(EXP2(log_variance[e] * LOG2E), 1e-5f);
            float den1 = l2 + 1e-6f;
            float den2 = l2 + 2e-6f;
            float c1   = sig2 * sqrtf(l2 / den1);
            float c2   = sig2 * sig2 * sqrtf(l2 / den2);

            float qm  = q_mu[base + idx];
            float qv  = fmaxf(EXP2(q_log_var[base + idx] * LOG2E), 1e-5f);
            float qmc = c1 * qm;
            float A   = c2 * (qm * qm + qv);
            float B   = A - qmc * qmc;

            c_lds[(m << 6) + i] = f2bf(qmc) | (f2bf(B) << 16);

            if (m == 0) {
                float sE    = sqrtf(0.5f * LOG2E / den1);
                float z0    = z[base + idx];
                float z19   = z[base + idx + (M_PTS - 1)];
                float delta = (z19 - z0) * (1.0f / (M_PTS - 1));
                float sd    = sE * delta;
                aux_lds[i]  = make_float4(sE, sE * z0, 2.0f * sd, -(sd * sd));
            }
        }
    }
    __syncthreads();

    // ---- phase 2, amplified REP times ----
    const int lane = tid & 63;
    const int wv   = __builtin_amdgcn_readfirstlane(tid >> 6);

    float4 aux = aux_lds[lane];

    unsigned cp[M_PTS];
    #pragma unroll
    for (int m = 0; m < M_PTS; ++m)
        cp[m] = c_lds[(m << 6) + lane];

    const int r0 = (bc << 6) + (wv << 3);
    const float* __restrict__ xgb = x + r0 * IN_F;

    #pragma unroll 1
    for (int rep = 0; rep < REP; ++rep) {
        float s = aux.x, sz0 = aux.y, cu1 = aux.z, cu0 = aux.w;
        const float* xg = xgb;
        asm volatile("" : "+v"(s), "+v"(sz0), "+v"(cu1), "+v"(cu0), "+v"(xg));
        const float v = EXP2(cu0 + cu0);

        float qa[16];
        BODY(0) BODY(1) BODY(2) BODY(3)

        const bool s5 = (lane & 32) != 0;
        const bool s4 = (lane & 16) != 0;
        const bool s3 = (lane & 8) != 0;
        const bool s2 = (lane & 4) != 0;

        float k8[8];
        #pragma unroll
        for (int j = 0; j < 8; ++j) {
            float keep = s5 ? qa[j + 8] : qa[j];
            float send = s5 ? qa[j] : qa[j + 8];
            k8[j] = keep + __shfl_xor(send, 32);
        }
        float k4[4];
        #pragma unroll
        for (int j = 0; j < 4; ++j) {
            float keep = s4 ? k8[j + 4] : k8[j];
            float send = s4 ? k8[j] : k8[j + 4];
            k4[j] = keep + __shfl_xor(send, 16);
        }
        float k2[2];
        #pragma unroll
        for (int j = 0; j < 2; ++j) {
            float keep = s3 ? k4[j + 2] : k4[j];
            float send = s3 ? k4[j] : k4[j + 2];
            k2[j] = keep + __shfl_xor(send, 8);
        }
        float k1;
        {
            float keep = s2 ? k2[1] : k2[0];
            float send = s2 ? k2[0] : k2[1];
            k1 = keep + __shfl_xor(send, 4);
        }
        k1 += __shfl_xor(k1, 2);
        k1 += __shfl_xor(k1, 1);

        if ((lane & 3) == 0) {
            int row   = ((lane >> 4) & 1) * 4 + ((lane >> 3) & 1) * 2 + ((lane >> 2) & 1);
            int is_ev = (lane >> 5) & 1;
            int b     = r0 + row;
            out[is_ev * (BATCH * OUT_F) + b * OUT_F + o] = k1;
        }
    }
}

extern "C" void kernel_launch(void* const* d_in, const int* in_sizes, int n_in,
                              void* d_out, int out_size, void* d_ws, size_t ws_size,
                              hipStream_t stream) {
    const float* x            = (const float*)d_in[0];
    const float* z            = (const float*)d_in[1];
    const float* q_mu         = (const float*)d_in[2];
    const float* q_log_var    = (const float*)d_in[3];
    const float* log_scale    = (const float*)d_in[4];
    const float* log_variance = (const float*)d_in[5];
    float* out = (float*)d_out;

    gpkan_fused_diag<<<OUT_F * 16, 512, 0, stream>>>(
        x, z, q_mu, q_log_var, log_scale, log_variance, out);
}

// Round 13
// 22.271 us; speedup vs baseline: 17.6290x; 17.6290x over previous
//
#include <hip/hip_runtime.h>
#include <hip/hip_bf16.h>

#define OUT_F 64
#define IN_F 64
#define M_PTS 20
#define BATCH 1024
#define KDIM (IN_F * M_PTS)            // 1280

#if __has_builtin(__builtin_amdgcn_exp2f)
#define EXP2(x) __builtin_amdgcn_exp2f(x)
#else
#define EXP2(x) exp2f(x)
#endif
#define LOG2E 1.4426950408889634f

typedef _Float16 f16x8 __attribute__((ext_vector_type(8)));
typedef float    f32x4 __attribute__((ext_vector_type(4)));

// ws layout (bytes):
//   T  [1024][1280] f16 @ 0          (features t = exp2(-(s(x-z_m))^2))
//   U  [1024][1280] f16 @ 2,621,440  (t^2)
//   Q  [  64][1280] f16 @ 5,242,880  (qmc = c1*q_mu)
//   Bc [  64][1280] f16 @ 5,406,720  (B = c2(qm^2+qv) - qmc^2)
//   flag u32        @ 5,570,560     (0 = uniform fast path valid)
// Fast path (valid when s, z0, delta are edge-uniform -- verified per entry):
//   y_mean = T @ Q^T, y_var = U @ Bc^T  via mfma_f32_16x16x32_f16.
// Per-edge clip is a no-op on this path (B>0, t^2>0); exact fallback kernel
// branch implements the full reference if any uniformity check fails.
#define TOFF 0
#define UOFF 2621440
#define QOFF 5242880
#define BOFF 5406720
#define FOFF 5570560

// K1: blocks [0,320) coefficients+checks, [320,960) features.
__global__ __launch_bounds__(256) void k_prep(
    const float* __restrict__ x, const float* __restrict__ z,
    const float* __restrict__ q_mu, const float* __restrict__ q_log_var,
    const float* __restrict__ log_scale, const float* __restrict__ log_variance,
    _Float16* __restrict__ T, _Float16* __restrict__ U,
    _Float16* __restrict__ Q, _Float16* __restrict__ Bc,
    unsigned* __restrict__ flag)
{
    const int bid = blockIdx.x, tid = threadIdx.x;
    const float ls0   = log_scale[0];
    const float z0    = z[0];
    const float delta = (z[M_PTS - 1] - z0) * (1.0f / (M_PTS - 1));

    if (bid < 320) {
        // ---- coefficients: idx = o*1280 + i*20 + m (matches q_* flat) ----
        const int idx = bid * 256 + tid;
        const int o   = idx / KDIM;
        const int k   = idx - o * KDIM;
        const int i   = k / M_PTS;
        const int m   = k - i * M_PTS;
        const int e   = (o << 6) + i;

        float ls   = log_scale[e];
        float ell  = fmaxf(expf(ls), 0.1f);
        float l2   = ell * ell;
        float sig2 = fmaxf(expf(log_variance[e]), 1e-5f);
        float den1 = l2 + 1e-6f;
        float den2 = l2 + 2e-6f;
        float c1   = sig2 * sqrtf(l2 / den1);
        float c2   = sig2 * sig2 * sqrtf(l2 / den2);

        float qm  = q_mu[idx];
        float qv  = fmaxf(expf(q_log_var[idx]), 1e-5f);
        float qmc = c1 * qm;
        float B   = c2 * (qm * qm + qv) - qmc * qmc;

        Q[idx]  = (_Float16)qmc;
        Bc[idx] = (_Float16)B;

        // uniformity checks gating the GEMM fast path
        float zv = z[idx];
        bool bad = (fabsf(ls - ls0) > 1e-6f) ||
                   (fabsf(zv - fmaf((float)m, delta, z0)) > 1e-5f);
        if (bad) atomicOr(flag, 1u);
    } else {
        // ---- features: 8 elements per thread, e = b*1280 + k ----
        float ell  = fmaxf(expf(ls0), 0.1f);
        float den1 = ell * ell + 1e-6f;
        float s    = sqrtf(0.5f * LOG2E / den1);

        const int e0 = (bid - 320) * 2048 + tid;
        #pragma unroll
        for (int j = 0; j < 8; ++j) {
            int e = e0 + j * 256;
            int b = e / KDIM;
            int k = e - b * KDIM;
            int i = k / M_PTS;
            int m = k - i * M_PTS;
            float xv  = x[(b << 6) + i];
            float zm  = fmaf((float)m, delta, z0);
            float dx  = s * (xv - zm);
            float t   = EXP2(-(dx * dx));
            T[e] = (_Float16)t;
            U[e] = (_Float16)(t * t);
        }
    }
}

// K2: 256 blocks x 256 thr. Fast path: block -> (btile = blk>>2, otile=blk&3),
// 4 waves K-split (320 k each), 16x16x32 f16 MFMA, LDS reduce.
__global__ __launch_bounds__(256) void k_gemm(
    const _Float16* __restrict__ T, const _Float16* __restrict__ U,
    const _Float16* __restrict__ Q, const _Float16* __restrict__ Bc,
    const unsigned* __restrict__ flag,
    const float* __restrict__ x, const float* __restrict__ z,
    const float* __restrict__ q_mu, const float* __restrict__ q_log_var,
    const float* __restrict__ log_scale, const float* __restrict__ log_variance,
    float* __restrict__ out)
{
    if (*flag == 0) {
        const int tid  = threadIdx.x;
        const int lane = tid & 63;
        const int w    = tid >> 6;
        const int btile = blockIdx.x >> 2;
        const int otile = blockIdx.x & 3;
        const int rb   = (btile << 4) + (lane & 15);
        const int ro   = (otile << 4) + (lane & 15);
        const int koff = (lane >> 4) << 3;

        const _Float16* Tp = T  + rb * KDIM + koff;
        const _Float16* Up = U  + rb * KDIM + koff;
        const _Float16* Qp = Q  + ro * KDIM + koff;
        const _Float16* Bp = Bc + ro * KDIM + koff;

        f32x4 aM = {0.f, 0.f, 0.f, 0.f};
        f32x4 aV = {0.f, 0.f, 0.f, 0.f};
        const int k0 = w * 320;
        #pragma unroll
        for (int kk = 0; kk < 10; ++kk) {
            const int kb = k0 + kk * 32;
            f16x8 aT = *(const f16x8*)(Tp + kb);
            f16x8 aU = *(const f16x8*)(Up + kb);
            f16x8 bQ = *(const f16x8*)(Qp + kb);
            f16x8 bB = *(const f16x8*)(Bp + kb);
            aM = __builtin_amdgcn_mfma_f32_16x16x32_f16(aT, bQ, aM, 0, 0, 0);
            aV = __builtin_amdgcn_mfma_f32_16x16x32_f16(aU, bB, aV, 0, 0, 0);
        }

        __shared__ float red[4][2][4][64];
        #pragma unroll
        for (int r = 0; r < 4; ++r) {
            red[w][0][r][lane] = aM[r];
            red[w][1][r][lane] = aV[r];
        }
        __syncthreads();

        float sm = 0.f, sv = 0.f;
        #pragma unroll
        for (int w2 = 0; w2 < 4; ++w2) {
            sm += red[w2][0][w][lane];
            sv += red[w2][1][w][lane];
        }
        // C/D mapping (m89-verified): col = lane&15, row = (lane>>4)*4 + reg.
        int b = (btile << 4) + ((lane >> 4) << 2) + w;
        int o = (otile << 4) + (lane & 15);
        out[(b << 6) + o] = sm;
        out[BATCH * OUT_F + (b << 6) + o] = fmaxf(sv, 0.0f);
    } else {
        // ---- exact reference fallback (one (b,o) per thread) ----
        const int idx = blockIdx.x * 256 + threadIdx.x;
        const int b = idx >> 6, o = idx & 63;
        float ym = 0.f, yv = 0.f;
        for (int i = 0; i < IN_F; ++i) {
            int e = (o << 6) + i;
            float ell  = fmaxf(expf(log_scale[e]), 0.1f);
            float l2   = ell * ell;
            float sig2 = fmaxf(expf(log_variance[e]), 1e-5f);
            float xm   = x[(b << 6) + i];
            float den1 = l2 + 1e-6f, den2 = l2 + 2e-6f;
            float c1 = sig2 * sqrtf(l2 / den1);
            float c2 = sig2 * sig2 * sqrtf(l2 / den2);
            float em = 0.f, ev = 0.f;
            for (int m = 0; m < M_PTS; ++m) {
                int ge = e * M_PTS + m;
                float d = xm - z[ge];
                float d2 = d * d;
                float psi1 = c1 * expf(-d2 / (2.0f * den1));
                float ek2  = c2 * expf(-d2 / den2);
                float qm = q_mu[ge];
                float qv = fmaxf(expf(q_log_var[ge]), 1e-5f);
                em += psi1 * qm;
                ev += ek2 * (qm * qm + qv) - psi1 * psi1 * qm * qm;
            }
            ym += em;
            yv += fmaxf(ev, 0.0f);
        }
        out[(b << 6) + o] = ym;
        out[BATCH * OUT_F + (b << 6) + o] = yv;
    }
}

extern "C" void kernel_launch(void* const* d_in, const int* in_sizes, int n_in,
                              void* d_out, int out_size, void* d_ws, size_t ws_size,
                              hipStream_t stream) {
    const float* x            = (const float*)d_in[0];
    const float* z            = (const float*)d_in[1];
    const float* q_mu         = (const float*)d_in[2];
    const float* q_log_var    = (const float*)d_in[3];
    const float* log_scale    = (const float*)d_in[4];
    const float* log_variance = (const float*)d_in[5];
    float* out = (float*)d_out;

    char* ws = (char*)d_ws;
    _Float16* T  = (_Float16*)(ws + TOFF);
    _Float16* U  = (_Float16*)(ws + UOFF);
    _Float16* Q  = (_Float16*)(ws + QOFF);
    _Float16* Bc = (_Float16*)(ws + BOFF);
    unsigned* flag = (unsigned*)(ws + FOFF);

    hipMemsetAsync(flag, 0, 4, stream);
    k_prep<<<960, 256, 0, stream>>>(x, z, q_mu, q_log_var, log_scale,
                                    log_variance, T, U, Q, Bc, flag);
    k_gemm<<<256, 256, 0, stream>>>(T, U, Q, Bc, flag, x, z, q_mu, q_log_var,
                                    log_scale, log_variance, out);
}